// Round 10
// baseline (11452.724 us; speedup 1.0000x reference)
//
#include <hip/hip_runtime.h>

#define WGSZ 1024
#define NWG  256   // 4 WGs per batch

namespace {
constexpr int kN = 2048, kH = 256, kOO = 4096, kGW = 512;
// ws float offsets; slots (256 ints) at 0
constexpr int WS_CONVS = 256;                    // 64*4096
constexpr int WS_ELAH  = WS_CONVS + 64*kOO;      // 64*256
constexpr int WS_ELAO  = WS_ELAH + 64*kH;
constexpr int WS_ELMH  = WS_ELAO + 64*kH;
constexpr int WS_ELMO  = WS_ELMH + 64*kH;
constexpr int WS_EBLH  = WS_ELMO + 64*kH;
constexpr int WS_EBLO  = WS_EBLH + 64*kH;
constexpr int WS_H0    = WS_EBLO + 64*kH;        // 2 parities * 64*256
constexpr int WS_H1    = WS_H0 + 2*64*kH;
constexpr int WS_DMH   = WS_H1 + 2*64*kH;
constexpr int WS_DVH   = WS_DMH + 64*kH;
// total = WS_DVH + 64*kH = 459,008 floats ~= 1.84 MB
}

// np.argmin(|centers - v|), first index on tie; centers in exact np fp32 order.
__device__ __forceinline__ int bin_idx(float v) {
  float t = fmaf(v, 5.0f, 63.5f);
  int i0 = (int)floorf(t);
  int c0 = i0 - 1; c0 = c0 < 0 ? 0 : (c0 > 127 ? 127 : c0);
  int c1 = i0;     c1 = c1 < 0 ? 0 : (c1 > 127 ? 127 : c1);
  int c2 = i0 + 1; c2 = c2 < 0 ? 0 : (c2 > 127 ? 127 : c2);
  float d0 = fabsf(__fmul_rn(__fadd_rn((float)(c0 - 64), 0.5f), 0.2f) - v);
  float d1 = fabsf(__fmul_rn(__fadd_rn((float)(c1 - 64), 0.5f), 0.2f) - v);
  float d2 = fabsf(__fmul_rn(__fadd_rn((float)(c2 - 64), 0.5f), 0.2f) - v);
  int best = c0; float bd = d0;
  if (d1 < bd) { bd = d1; best = c1; }
  if (d2 < bd) { bd = d2; best = c2; }
  return best;
}

// numpy pairwise_sum, exact replication for n=128 / 256.
__device__ __forceinline__ float np_pw128(const float* a) {
  float r0=a[0],r1=a[1],r2=a[2],r3=a[3],r4=a[4],r5=a[5],r6=a[6],r7=a[7];
  for (int i = 8; i < 128; i += 8) {
    r0=__fadd_rn(r0,a[i+0]); r1=__fadd_rn(r1,a[i+1]);
    r2=__fadd_rn(r2,a[i+2]); r3=__fadd_rn(r3,a[i+3]);
    r4=__fadd_rn(r4,a[i+4]); r5=__fadd_rn(r5,a[i+5]);
    r6=__fadd_rn(r6,a[i+6]); r7=__fadd_rn(r7,a[i+7]);
  }
  return __fadd_rn(__fadd_rn(__fadd_rn(r0,r1),__fadd_rn(r2,r3)),
                   __fadd_rn(__fadd_rn(r4,r5),__fadd_rn(r6,r7)));
}
__device__ __forceinline__ float np_sum256(const float* a) {
  return __fadd_rn(np_pw128(a), np_pw128(a + 128));
}

__device__ __forceinline__ float sig_np(float x) {
  return __fdiv_rn(1.0f, __fadd_rn(1.0f, expf(-x)));
}

// Exact ascending-k K=256 dot; float4 loads, unroll 8.
__device__ __forceinline__ float dot256(const float* __restrict__ w, const float* x) {
  const float4* w4 = (const float4*)w;
  const float4* x4 = (const float4*)x;
  float acc = 0.0f;
  #pragma unroll 8
  for (int i = 0; i < 64; ++i) {
    float4 wv = w4[i], xv = x4[i];
    acc = fmaf(wv.x, xv.x, acc);
    acc = fmaf(wv.y, xv.y, acc);
    acc = fmaf(wv.z, xv.z, acc);
    acc = fmaf(wv.w, xv.w, acc);
  }
  return acc;
}
__device__ __forceinline__ float sum256(const float* __restrict__ w) {
  const float4* w4 = (const float4*)w;
  float acc = 0.0f;
  #pragma unroll 8
  for (int i = 0; i < 64; ++i) {
    float4 wv = w4[i];
    acc = __fadd_rn(acc, wv.x);
    acc = __fadd_rn(acc, wv.y);
    acc = __fadd_rn(acc, wv.z);
    acc = __fadd_rn(acc, wv.w);
  }
  return acc;
}

// Poison-safe grid barrier over 256 WGs (monotone gen; 0xAAAAAAAA < 1 as int).
__device__ __forceinline__ void gbar(int* slots, int gen) {
  __syncthreads();
  if (threadIdx.x < 64) {
    if (threadIdx.x == 0) {
      __threadfence();
      __hip_atomic_store(&slots[blockIdx.x], gen, __ATOMIC_RELEASE, __HIP_MEMORY_SCOPE_AGENT);
    }
    for (;;) {
      int v0 = __hip_atomic_load(&slots[threadIdx.x      ], __ATOMIC_ACQUIRE, __HIP_MEMORY_SCOPE_AGENT);
      int v1 = __hip_atomic_load(&slots[threadIdx.x +  64], __ATOMIC_ACQUIRE, __HIP_MEMORY_SCOPE_AGENT);
      int v2 = __hip_atomic_load(&slots[threadIdx.x + 128], __ATOMIC_ACQUIRE, __HIP_MEMORY_SCOPE_AGENT);
      int v3 = __hip_atomic_load(&slots[threadIdx.x + 192], __ATOMIC_ACQUIRE, __HIP_MEMORY_SCOPE_AGENT);
      if (__all((v0 >= gen) && (v1 >= gen) && (v2 >= gen) && (v3 >= gen))) break;
      __builtin_amdgcn_s_sleep(2);
    }
    __threadfence();
  }
  __syncthreads();
}

__global__ __launch_bounds__(WGSZ, 4) void planner_kernel(
    const float* __restrict__ inp_start, const float* __restrict__ map_pts,
    const float* __restrict__ ela_w1, const float* __restrict__ ela_w2,
    const float* __restrict__ conv_w, const float* __restrict__ elm_w1,
    const float* __restrict__ elm_w2, const float* __restrict__ ebl_w1,
    const float* __restrict__ ebl_w2, const float* __restrict__ lstm_wih,
    const float* __restrict__ lstm_whh, const float* __restrict__ dm_w1,
    const float* __restrict__ dm_w2, const float* __restrict__ dv_w1,
    const float* __restrict__ dv_w2, float* __restrict__ g_out,
    float* __restrict__ ws) {
  const int b   = blockIdx.x >> 2;   // batch
  const int q   = blockIdx.x & 3;    // quarter
  const int tid = threadIdx.x;
  int* slots = (int*)ws;
  int gen = 0;

  __shared__ unsigned s_mask[kGW];
  __shared__ __align__(16) float s_cw[800];
  __shared__ __align__(16) float s_gate[256];   // 4 gates x 64 j (this WG's quarter)
  __shared__ __align__(16) float s_c0[64], s_c1[64];
  __shared__ __align__(16) float s_h1L[kH];
  __shared__ __align__(16) float s_tmp[512];
  __shared__ __align__(16) float s_r[kH];
  __shared__ __align__(16) float s_dmhL[kH], s_dvhL[kH];
  __shared__ float s_anchor[3], s_cs[2], s_g6[6];
  __shared__ float s_mu, s_den;

  // ---- init (local; all 4 WGs of a batch compute identical anchor) ----
  if (tid == 0) {
    float a2 = inp_start[b * 3 + 2];
    s_anchor[0] = inp_start[b * 3 + 0];
    s_anchor[1] = inp_start[b * 3 + 1];
    s_anchor[2] = a2;
    s_cs[0] = (float)cos((double)a2);
    s_cs[1] = (float)sin((double)a2);
  }
  if (q == 0 && tid < 3) {
    g_out[b * 96 + tid] = inp_start[b * 3 + tid];
    g_out[6144 + b * 96 + tid] = 0.01f;
  }
  __syncthreads();

  const float* wsf = ws;  // alias for reads

  for (int k = 0; k < 28; ++k) {
    const int st = k / 7, a = k % 7;
    const bool a0f = (a == 0);
    const int pw = k & 1, pr = pw ^ 1;

    // ======== seg1: OGM (WG-local, full) + conv quarter + ela_h quarter ========
    for (int w = tid; w < kGW; w += WGSZ) s_mask[w] = 0u;
    for (int w = tid; w < 800; w += WGSZ) s_cw[w] = conv_w[st * 800 + w];
    __syncthreads();
    {
      float ax = s_anchor[0], ay = s_anchor[1], cc = s_cs[0], ss = s_cs[1];
      for (int n = tid; n < kN; n += WGSZ) {
        float mx = __fadd_rn(map_pts[n],      -ax);
        float my = __fadd_rn(map_pts[kN + n], -ay);
        float px = fmaf(ss, my, __fmul_rn(cc, mx));
        float py = fmaf(cc, my, -__fmul_rn(ss, mx));
        bool outb = (fabsf(px) > 12.8f) || (fabsf(py) > 12.8f);
        px = outb ? 0.0f : px;
        py = outb ? 0.0f : py;
        int xi = bin_idx(px), yi = bin_idx(py);
        atomicOr(&s_mask[xi * 4 + (yi >> 5)], 1u << (yi & 31));
      }
    }
    __syncthreads();
    {   // conv: 1024 pixels per WG (quarter q)
      int p = q * 1024 + tid;
      int oy = p >> 6, ox = p & 63;
      unsigned occ = 0u;
      for (int ky = 0; ky < 5; ++ky) {
        int y = 2 * oy - 2 + ky;
        if ((unsigned)y >= 128u) continue;
        const unsigned* row = &s_mask[y * 4];
        for (int kx = 0; kx < 5; ++kx) {
          int x = 2 * ox - 2 + kx;
          if ((unsigned)x >= 128u) continue;
          if ((row[x >> 5] >> (x & 31)) & 1u) occ |= 1u << (ky * 5 + kx);
        }
      }
      float csum = 0.0f;
      for (int o = 0; o < 8; ++o) {
        float acc = 0.0f;
        const float* wo = s_cw + o * 100;
        for (int ci = 0; ci < 4; ++ci) {
          const float* wc = wo + ci * 25;
          #pragma unroll
          for (int t = 0; t < 25; ++t)
            if (occ & (1u << t)) acc = __fadd_rn(acc, wc[t]);
        }
        float th = tanhf(acc);
        csum = (o == 0) ? th : __fadd_rn(csum, th);
      }
      ws[WS_CONVS + b * kOO + p] = csum;
    }
    if (tid < 64) {  // ela hidden rows q*64..q*64+63
      int r = q * 64 + tid;
      const float* w1r = ela_w1 + (st * kH + r) * 3;
      float h = fmaf(s_anchor[2], w1r[2],
                fmaf(s_anchor[1], w1r[1], __fmul_rn(s_anchor[0], w1r[0])));
      ws[WS_ELAH + b * kH + r] = fmaxf(h, 0.0f);
    }
    gbar(slots, ++gen);

    // ======== seg2: ela_o (wave0) + elm_h (waves 4-7, 16 rows each) ========
    if (tid < 64) {
      int r = q * 64 + tid;
      ws[WS_ELAO + b * kH + r] =
          dot256(ela_w2 + (st * kH + r) * kH, wsf + WS_ELAH + b * kH);
    }
    if (tid >= 256 && tid < 512 && (tid & 3) == 0) {
      int r = q * 64 + ((tid - 256) >> 2);
      const float4* wr = (const float4*)(elm_w1 + (st * kH + r) * kOO);
      const float4* xr = (const float4*)(wsf + WS_CONVS + b * kOO);
      float acc2 = 0.0f;
      #pragma unroll 8
      for (int i = 0; i < 1024; ++i) {
        float4 wv = wr[i], xv = xr[i];
        acc2 = fmaf(wv.x, xv.x, acc2);
        acc2 = fmaf(wv.y, xv.y, acc2);
        acc2 = fmaf(wv.z, xv.z, acc2);
        acc2 = fmaf(wv.w, xv.w, acc2);
      }
      ws[WS_ELMH + b * kH + r] = fmaxf(acc2, 0.0f);
    }
    gbar(slots, ++gen);

    // ======== seg3: elm_o ========
    if (tid < 64) {
      int r = q * 64 + tid;
      ws[WS_ELMO + b * kH + r] =
          dot256(elm_w2 + (st * kH + r) * kH, wsf + WS_ELMH + b * kH);
    }
    gbar(slots, ++gen);

    // ======== seg4: ebl_h (K=512, single ascending chain) ========
    if (tid < 64) {
      int r = q * 64 + tid;
      const float4* w4 = (const float4*)(ebl_w1 + (st * kH + r) * 512);
      const float4* xa = (const float4*)(wsf + WS_ELAO + b * kH);
      const float4* xm = (const float4*)(wsf + WS_ELMO + b * kH);
      float acc = 0.0f;
      #pragma unroll 8
      for (int i = 0; i < 64; ++i) {
        float4 wv = w4[i], xv = xa[i];
        acc = fmaf(wv.x, xv.x, acc); acc = fmaf(wv.y, xv.y, acc);
        acc = fmaf(wv.z, xv.z, acc); acc = fmaf(wv.w, xv.w, acc);
      }
      #pragma unroll 8
      for (int i = 0; i < 64; ++i) {
        float4 wv = w4[64 + i], xv = xm[i];
        acc = fmaf(wv.x, xv.x, acc); acc = fmaf(wv.y, xv.y, acc);
        acc = fmaf(wv.z, xv.z, acc); acc = fmaf(wv.w, xv.w, acc);
      }
      ws[WS_EBLH + b * kH + r] = fmaxf(acc, 0.0f);
    }
    gbar(slots, ++gen);

    // ======== seg5: ebl_o ========
    if (tid < 64) {
      int r = q * 64 + tid;
      ws[WS_EBLO + b * kH + r] =
          dot256(ebl_w2 + (st * kH + r) * kH, wsf + WS_EBLH + b * kH);
    }
    gbar(slots, ++gen);

    // ======== seg6: LSTM layer0 (rows: all 4 gates for j in quarter) ========
    if (tid < 256) {
      int g = tid >> 6, jj = tid & 63;
      int row = g * 256 + q * 64 + jj;
      const float* wf = lstm_wih + ((st * 2 + 0) * 1024 + row) * kH;
      const float* wh = lstm_whh + ((st * 2 + 0) * 1024 + row) * kH;
      float A = dot256(wf, wsf + WS_EBLO + b * kH);
      float B = a0f ? sum256(wh) : dot256(wh, wsf + WS_H0 + pr * 16384 + b * kH);
      s_gate[g * 64 + jj] = __fadd_rn(A, B);
    }
    __syncthreads();
    if (tid < 64) {
      int j = q * 64 + tid;
      float gi = s_gate[tid], gf = s_gate[64 + tid];
      float gg = s_gate[128 + tid], go = s_gate[192 + tid];
      float cprev = a0f ? 1.0f : s_c0[tid];
      float cl = __fadd_rn(__fmul_rn(sig_np(gf), cprev),
                           __fmul_rn(sig_np(gi), tanhf(gg)));
      float hl = __fmul_rn(sig_np(go), tanhf(cl));
      s_c0[tid] = cl;
      ws[WS_H0 + pw * 16384 + b * kH + j] = hl;
    }
    gbar(slots, ++gen);

    // ======== seg7: LSTM layer1 ========
    if (tid < 256) {
      int g = tid >> 6, jj = tid & 63;
      int row = g * 256 + q * 64 + jj;
      const float* wf = lstm_wih + ((st * 2 + 1) * 1024 + row) * kH;
      const float* wh = lstm_whh + ((st * 2 + 1) * 1024 + row) * kH;
      float A = dot256(wf, wsf + WS_H0 + pw * 16384 + b * kH);
      float B = a0f ? sum256(wh) : dot256(wh, wsf + WS_H1 + pr * 16384 + b * kH);
      s_gate[g * 64 + jj] = __fadd_rn(A, B);
    }
    __syncthreads();
    if (tid < 64) {
      int j = q * 64 + tid;
      float gi = s_gate[tid], gf = s_gate[64 + tid];
      float gg = s_gate[128 + tid], go = s_gate[192 + tid];
      float cprev = a0f ? 1.0f : s_c1[tid];
      float cl = __fadd_rn(__fmul_rn(sig_np(gf), cprev),
                           __fmul_rn(sig_np(gi), tanhf(gg)));
      float hl = __fmul_rn(sig_np(go), tanhf(cl));
      s_c1[tid] = cl;
      ws[WS_H1 + pw * 16384 + b * kH + j] = hl;
    }
    gbar(slots, ++gen);

    // ======== seg8: LN (redundant per WG) + r + dm/dv hidden quarter ========
    if (tid < 64)
      ((float4*)s_h1L)[tid] = ((const float4*)(wsf + WS_H1 + pw * 16384 + b * kH))[tid];
    __syncthreads();
    if (tid == 0) s_mu = __fdiv_rn(np_sum256(s_h1L), 256.0f);
    __syncthreads();
    if (tid < kH) {
      float d = __fadd_rn(s_h1L[tid], -s_mu);
      s_tmp[tid] = d;
      s_tmp[256 + tid] = __fmul_rn(d, d);
    }
    __syncthreads();
    if (tid == 0) {
      float v = __fdiv_rn(np_sum256(s_tmp + 256), 256.0f);
      s_den = __fsqrt_rn(__fadd_rn(v, 1e-5f));
    }
    __syncthreads();
    if (tid < kH) {
      float r = __fadd_rn(__fdiv_rn(s_tmp[tid], s_den), wsf[WS_EBLO + b * kH + tid]);
      s_r[tid] = fmaxf(r, 0.0f);
    }
    __syncthreads();
    if (tid < 128) {
      int jj = tid & 63;
      int r = q * 64 + jj;
      if (tid < 64) {
        ws[WS_DMH + b * kH + r] = fmaxf(dot256(dm_w1 + (st * kH + r) * kH, s_r), 0.0f);
      } else {
        ws[WS_DVH + b * kH + r] = fmaxf(dot256(dv_w1 + (st * kH + r) * kH, s_r), 0.0f);
      }
    }
    gbar(slots, ++gen);

    // ======== seg9: heads + anchor (redundant, bit-exact) + outputs ========
    if (tid < 64) {
      ((float4*)s_dmhL)[tid] = ((const float4*)(wsf + WS_DMH + b * kH))[tid];
      ((float4*)s_dvhL)[tid] = ((const float4*)(wsf + WS_DVH + b * kH))[tid];
    }
    __syncthreads();
    if (tid < 6) {
      int d = tid % 3; bool isv = tid >= 3;
      s_g6[tid] = dot256(((isv ? dv_w2 : dm_w2) + (st * 3 + d) * kH),
                         (isv ? s_dvhL : s_dmhL));
    }
    __syncthreads();
    if (tid == 0) {
      const float dlmf[3] = {2.0f, 2.0f, 0.5f};
      for (int d = 0; d < 3; ++d) {
        float avn = __fadd_rn(s_anchor[d], __fmul_rn(tanhf(s_g6[d]), dlmf[d]));
        float vvn = __fmul_rn(sig_np(s_g6[3 + d]), 0.1f);
        s_anchor[d] = avn;
        if (q == 0) {
          int o = ((b * 4 + st) * 8 + (a + 1)) * 3 + d;
          g_out[o] = avn;
          g_out[6144 + o] = vvn;
          if (a == 6 && st < 3) {
            int o2 = ((b * 4 + st + 1) * 8 + 0) * 3 + d;
            g_out[o2] = avn;
            g_out[6144 + o2] = vvn;
          }
        }
      }
      s_cs[0] = (float)cos((double)s_anchor[2]);
      s_cs[1] = (float)sin((double)s_anchor[2]);
    }
    __syncthreads();
  }
}

extern "C" void kernel_launch(void* const* d_in, const int* in_sizes, int n_in,
                              void* d_out, int out_size, void* d_ws, size_t ws_size,
                              hipStream_t stream) {
  (void)in_sizes; (void)n_in; (void)out_size; (void)ws_size;
  planner_kernel<<<dim3(NWG), dim3(WGSZ), 0, stream>>>(
      (const float*)d_in[0],  (const float*)d_in[1],  (const float*)d_in[2],
      (const float*)d_in[3],  (const float*)d_in[4],  (const float*)d_in[5],
      (const float*)d_in[6],  (const float*)d_in[7],  (const float*)d_in[8],
      (const float*)d_in[9],  (const float*)d_in[10], (const float*)d_in[11],
      (const float*)d_in[12], (const float*)d_in[13], (const float*)d_in[14],
      (float*)d_out, (float*)d_ws);
}